// Round 4
// baseline (889.248 us; speedup 1.0000x reference)
//
#include <hip/hip_runtime.h>

// x (64,32,4096) fp32; emb (1024,256) fp32.
// Row n = bl*16 + v (bl = b*32+l); z_flat[n][a] = x[bl*4096 + a*16 + v].
// Outputs FLOAT32, concat: z_q [8388608] (b,l,a,v), decoder_input [8388608]
// (== z_q forward), tokens [32768] (b,l,v).
//
// The np reference computes dist = z_sq + e_sq - 2*(z@e.T) entirely in float32.
// z_sq ~ 256 dominates: score ulp is ~3.05e-5, so near-tie resolution depends on
// the f32 rounding pattern. We emulate: s = fl32(fl32(zsq_f32+esq_f32[j]) - 2*dot),
// with f64-dot re-emulation for rows whose margin <= TAU, first-index tie-break.
#define A_DIM 256
#define VOCAB 1024
#define ZQ_ELEMS ((size_t)8388608)
#define BM 128
#define BN 128
#define BK 32
#define TAU 2.0e-4f

__global__ __launch_bounds__(256) void prep_kernel(const float* __restrict__ emb,
                                                   float* __restrict__ e_sq32) {
    int j = blockIdx.x * 256 + threadIdx.x;
    if (j < VOCAB) {
        const float4* row = (const float4*)(emb + (size_t)j * A_DIM);
        double s = 0.0;
        #pragma unroll 4
        for (int t = 0; t < A_DIM / 4; ++t) {
            float4 f = row[t];
            // np squares in f32 then sums; f32-rounded squares differ from exact
            // by ~5e-13 total here — far below any rounding boundary that matters.
            float sx = f.x * f.x, sy = f.y * f.y, sz = f.z * f.z, sw = f.w * f.w;
            s += (double)sx + (double)sy + (double)sz + (double)sw;
        }
        e_sq32[j] = (float)s;
    }
}

struct SmemB {
    union {
        struct { float zs[BK][BM]; float es[BK][BN]; };            // GEMM (32 KB)
        float4 mbuf[BM][16];                                        // merge (32 KB)
        struct { double zrow[A_DIM]; float rbest[256]; int ridx[256]; };  // refine
    };
    int tok[BM];
    int flagrows[BM];
    int nflag;
    float  zsq[BM];        // fl32 of per-row sum z^2 (persists all phases)
    double zsqp2[BM];      // partial for zsq reduction
};

__global__ __launch_bounds__(256) void main_kernel(const float* __restrict__ x,
                                                   const float* __restrict__ emb,
                                                   const float* __restrict__ e_sq32,
                                                   float* __restrict__ out) {
    __shared__ SmemB sm;
    const int tid = threadIdx.x;
    const int tx = tid & 15;         // cand dim
    const int ty = tid >> 4;         // row dim
    const int blk = blockIdx.x;      // 0..255
    const int row0 = blk * BM;
    const int bl0 = row0 >> 4;       // 8 (b,l) groups per block
    const int zrow_id = tid & 127;   // for zsq accumulation
    const int zhalf   = tid >> 7;

    if (tid == 0) sm.nflag = 0;

    // ---- Phase 1: fp32 scoring GEMM with emulated-np-f32 score + top-2 ----
    float v1[8], v2[8];
    int   i1[8], i2[8];
    #pragma unroll
    for (int r = 0; r < 8; ++r) { v1[r] = 3.0e38f; v2[r] = 3.0e38f; i1[r] = 0; i2[r] = 0; }

    double zsqp = 0.0;  // this thread's partial of sum z^2 for row zrow_id

    for (int ct = 0; ct < VOCAB / BN; ++ct) {
        float acc[8][8];
        #pragma unroll
        for (int rr = 0; rr < 8; ++rr)
            #pragma unroll
            for (int cc = 0; cc < 8; ++cc) acc[rr][cc] = 0.0f;

        for (int kt = 0; kt < A_DIM / BK; ++kt) {
            __syncthreads();
            // stage zs[k][row]
            #pragma unroll
            for (int t = 0; t < 4; ++t) {
                int f = tid + t * 256;            // 0..1023 float4s
                int v4 = f & 3;
                int g  = (f >> 2) & 7;
                int kk = f >> 5;
                float4 s4 = *(const float4*)(x + (size_t)(bl0 + g) * 4096 + kt * 512 + kk * 16 + v4 * 4);
                *(float4*)&sm.zs[kk][g * 16 + v4 * 4] = s4;
            }
            // stage es[k][cand] (transposed)
            #pragma unroll
            for (int t = 0; t < 4; ++t) {
                int f = tid + t * 256;
                int c  = f & 127;
                int k4 = f >> 7;
                float4 s4 = *(const float4*)(emb + (size_t)(ct * BN + c) * A_DIM + kt * BK + k4 * 4);
                sm.es[k4 * 4 + 0][c] = s4.x;
                sm.es[k4 * 4 + 1][c] = s4.y;
                sm.es[k4 * 4 + 2][c] = s4.z;
                sm.es[k4 * 4 + 3][c] = s4.w;
            }
            __syncthreads();

            #pragma unroll 2
            for (int kk = 0; kk < BK; ++kk) {
                float4 za = *(float4*)&sm.zs[kk][ty * 4];
                float4 zb = *(float4*)&sm.zs[kk][64 + ty * 4];
                float4 ea = *(float4*)&sm.es[kk][tx * 4];
                float4 eb = *(float4*)&sm.es[kk][64 + tx * 4];
                float zv[8] = {za.x, za.y, za.z, za.w, zb.x, zb.y, zb.z, zb.w};
                float ev[8] = {ea.x, ea.y, ea.z, ea.w, eb.x, eb.y, eb.z, eb.w};
                #pragma unroll
                for (int rr = 0; rr < 8; ++rr)
                    #pragma unroll
                    for (int cc = 0; cc < 8; ++cc)
                        acc[rr][cc] = fmaf(zv[rr], ev[cc], acc[rr][cc]);
            }

            // accumulate z^2 partials from the staged tile (ct==0 covers full K)
            if (ct == 0) {
                #pragma unroll
                for (int k = 0; k < 16; ++k) {
                    float zf = sm.zs[zhalf * 16 + k][zrow_id];
                    float zf2 = zf * zf;          // np squares in f32
                    zsqp += (double)zf2;
                }
            }
        }

        if (ct == 0) {
            // finalize zsq_f32 per row
            if (zhalf == 1) sm.zsqp2[zrow_id] = zsqp;
            __syncthreads();
            if (zhalf == 0) sm.zsq[zrow_id] = (float)(zsqp + sm.zsqp2[zrow_id]);
            __syncthreads();
        }

        // emulated-np-f32 scores + top-2 (per-thread candidate order ascending)
        float esqv[8];
        #pragma unroll
        for (int cc = 0; cc < 8; ++cc) {
            int c = ct * BN + (cc >> 2) * 64 + tx * 4 + (cc & 3);
            esqv[cc] = e_sq32[c];
        }
        #pragma unroll
        for (int rr = 0; rr < 8; ++rr) {
            int R = (rr >> 2) * 64 + ty * 4 + (rr & 3);
            float zq = sm.zsq[R];
            #pragma unroll
            for (int cc = 0; cc < 8; ++cc) {
                int c = ct * BN + (cc >> 2) * 64 + tx * 4 + (cc & 3);
                float A = zq + esqv[cc];                    // fl32(zsq + esq)
                float s = fmaf(-2.0f, acc[rr][cc], A);      // fl32(A - 2*dot)
                if (s < v1[rr]) { v2[rr] = v1[rr]; i2[rr] = i1[rr]; v1[rr] = s; i1[rr] = c; }
                else if (s < v2[rr]) { v2[rr] = s; i2[rr] = c; }
            }
        }
    }

    // ---- Phase 2: cross-thread merge per row ----
    __syncthreads();
    #pragma unroll
    for (int rr = 0; rr < 8; ++rr) {
        int r = (rr >> 2) * 64 + ty * 4 + (rr & 3);
        float4 m;
        m.x = v1[rr]; m.y = __int_as_float(i1[rr]);
        m.z = v2[rr]; m.w = __int_as_float(i2[rr]);
        sm.mbuf[r][tx] = m;
    }
    __syncthreads();
    if (tid < BM) {
        int r = tid;
        float V1 = 3.0e38f, V2 = 3.0e38f;
        int I1 = 0, I2 = 0;
        for (int t = 0; t < 16; ++t) {
            float4 m = sm.mbuf[r][t];
            float a1 = m.x; int a1i = __float_as_int(m.y);
            float a2 = m.z; int a2i = __float_as_int(m.w);
            if (a1 < V1 || (a1 == V1 && a1i < I1)) { V2 = V1; I2 = I1; V1 = a1; I1 = a1i; }
            else if (a1 < V2 || (a1 == V2 && a1i < I2)) { V2 = a1; I2 = a1i; }
            if (a2 < V1 || (a2 == V1 && a2i < I1)) { V2 = V1; I2 = I1; V1 = a2; I1 = a2i; }
            else if (a2 < V2 || (a2 == V2 && a2i < I2)) { V2 = a2; I2 = a2i; }
        }
        sm.tok[r] = I1;
        if (V2 - V1 <= TAU) {
            int pos = atomicAdd(&sm.nflag, 1);
            sm.flagrows[pos] = r;
        }
    }
    __syncthreads();

    // ---- Phase 3: f64-dot re-emulation of near-tie rows (~3.5 rows/block) ----
    const int nf = sm.nflag;
    for (int i = 0; i < nf; ++i) {
        const int rl = sm.flagrows[i];
        const int bl = bl0 + (rl >> 4);
        const int v  = rl & 15;
        const float zqrow = sm.zsq[rl];
        sm.zrow[tid] = (double)x[(size_t)bl * 4096 + (size_t)tid * 16 + v];
        __syncthreads();
        float bv = 3.0e38f; int bi = 0;
        #pragma unroll
        for (int cc = 0; cc < 4; ++cc) {
            int c = tid * 4 + cc;
            const float4* er = (const float4*)(emb + (size_t)c * A_DIM);
            double dot = 0.0;
            #pragma unroll 8
            for (int k4 = 0; k4 < A_DIM / 4; ++k4) {
                float4 f = er[k4];
                dot = fma((double)f.x, sm.zrow[k4 * 4 + 0], dot);
                dot = fma((double)f.y, sm.zrow[k4 * 4 + 1], dot);
                dot = fma((double)f.z, sm.zrow[k4 * 4 + 2], dot);
                dot = fma((double)f.w, sm.zrow[k4 * 4 + 3], dot);
            }
            float A = zqrow + e_sq32[c];        // fl32(zsq + esq)
            float D = (float)(2.0 * dot);       // fl32(2*dot), correctly rounded
            float s = A - D;                    // fl32(A - D)
            if (s < bv) { bv = s; bi = c; }     // ascending c: strict < keeps first
        }
        sm.rbest[tid] = bv; sm.ridx[tid] = bi;
        __syncthreads();
        if (tid == 0) {
            float BV = sm.rbest[0]; int BI = sm.ridx[0];
            for (int t = 1; t < 256; ++t) {
                float vv = sm.rbest[t];
                if (vv < BV) { BV = vv; BI = sm.ridx[t]; }  // ascending c blocks
            }
            sm.tok[rl] = BI;
        }
        __syncthreads();
    }

    // ---- Phase 4: tokens as float32 ----
    if (tid < BM) {
        out[2 * ZQ_ELEMS + (size_t)(row0 + tid)] = (float)sm.tok[tid];
    }
    __syncthreads();

    // ---- Phase 5: z_q and decoder_input (float32) ----
    const int a = tid;  // 0..255
    for (int g = 0; g < 8; ++g) {
        __align__(16) float h[16];
        #pragma unroll
        for (int v = 0; v < 16; ++v) {
            h[v] = emb[(size_t)sm.tok[g * 16 + v] * A_DIM + a];
        }
        size_t base = ((size_t)(bl0 + g) * A_DIM + a) * 16;
        float4* p0 = (float4*)(out + base);
        float4* p1 = (float4*)(out + ZQ_ELEMS + base);
        #pragma unroll
        for (int q = 0; q < 4; ++q) {
            float4 val = *(float4*)&h[q * 4];
            p0[q] = val;
            p1[q] = val;
        }
    }
}

extern "C" void kernel_launch(void* const* d_in, const int* in_sizes, int n_in,
                              void* d_out, int out_size, void* d_ws, size_t ws_size,
                              hipStream_t stream) {
    (void)in_sizes; (void)n_in; (void)out_size; (void)ws_size;
    const float* x   = (const float*)d_in[0];
    const float* emb = (const float*)d_in[1];
    float* out = (float*)d_out;
    float* e_sq32 = (float*)d_ws;

    prep_kernel<<<4, 256, 0, stream>>>(emb, e_sq32);
    main_kernel<<<256, 256, 0, stream>>>(x, emb, e_sq32, out);
}

// Round 5
// 685.202 us; speedup vs baseline: 1.2978x; 1.2978x over previous
//
#include <hip/hip_runtime.h>

// x (64,32,4096) fp32; emb (1024,256) fp32.
// Row n = bl*16 + v (bl = b*32+l); z_flat[n][a] = x[bl*4096 + a*16 + v].
// Outputs FLOAT32, concat: z_q [8388608] (b,l,a,v), decoder_input [8388608]
// (== z_q forward), tokens [32768] (b,l,v).
//
// np reference computes dist = z_sq + e_sq - 2*(z@e.T) in float32; z_sq ~ 256
// dominates (score ulp ~3.05e-5). We emulate f32 rounding; rows with top-2
// margin <= TAU get an exact (f64-dot) re-emulation with first-index tie-break.
//
// R5: BM 128->64, BN 128->256 (same 8x8/thread tile), grid 512 -> 2 blocks/CU
// (2 waves/SIMD latency hiding) + register prefetch of next k-tile.
#define A_DIM 256
#define VOCAB 1024
#define ZQ_ELEMS ((size_t)8388608)
#define BM 64
#define BN 256
#define BK 32
#define NCT (VOCAB / BN)   // 4
#define NKT (A_DIM / BK)   // 8
#define TAU 2.0e-4f

__global__ __launch_bounds__(256) void prep_kernel(const float* __restrict__ emb,
                                                   float* __restrict__ e_sq32) {
    int j = blockIdx.x * 256 + threadIdx.x;
    if (j < VOCAB) {
        const float4* row = (const float4*)(emb + (size_t)j * A_DIM);
        double s = 0.0;
        #pragma unroll 4
        for (int t = 0; t < A_DIM / 4; ++t) {
            float4 f = row[t];
            float sx = f.x * f.x, sy = f.y * f.y, sz = f.z * f.z, sw = f.w * f.w;
            s += (double)sx + (double)sy + (double)sz + (double)sw;
        }
        e_sq32[j] = (float)s;
    }
}

struct Smem {
    union {
        struct { float zs[BK][BM]; float es[BK][BN]; };             // 8K + 32K GEMM
        float4 mbuf[BM][32];                                         // 32K merge
        struct { double zrow[A_DIM]; float rbest[256]; int ridx[256]; };  // refine
    };
    double zsqp_s[4][BM];   // zsq partials (2 KB)
    float  zsq[BM];
    int    tok[BM];
    int    flagrows[BM];
    int    nflag;
};

__global__ __launch_bounds__(256, 2) void main_kernel(const float* __restrict__ x,
                                                      const float* __restrict__ emb,
                                                      const float* __restrict__ e_sq32,
                                                      float* __restrict__ out) {
    __shared__ Smem sm;
    const int tid = threadIdx.x;
    const int tx = tid & 31;            // cand dim (32 col-threads)
    const int ty = tid >> 5;            // row dim (8 row-threads)
    const int blk = blockIdx.x;         // 0..511
    const int row0 = blk * BM;
    const int bl0 = row0 >> 4;          // 4 (b,l) groups per block
    const int zrow_id = tid & 63;       // zsq: row
    const int zq4     = tid >> 6;       // zsq: k-quarter 0..3 (wave-uniform)

    if (tid == 0) sm.nflag = 0;

    // ---- Phase 1: fp32 scoring GEMM, emulated-np-f32 score, per-thread top-2 ----
    float v1[8], v2[8];
    int   i1[8], i2[8];
    #pragma unroll
    for (int r = 0; r < 8; ++r) { v1[r] = 3.0e38f; v2[r] = 3.0e38f; i1[r] = 0; i2[r] = 0; }

    double zsqp = 0.0;
    float4 zpf[2];   // prefetch regs: z tile (2 float4/thread)
    float4 epf[8];   // prefetch regs: e tile (8 float4/thread)

    for (int ct = 0; ct < NCT; ++ct) {
        float acc[8][8];
        #pragma unroll
        for (int rr = 0; rr < 8; ++rr)
            #pragma unroll
            for (int cc = 0; cc < 8; ++cc) acc[rr][cc] = 0.0f;

        for (int kt = 0; kt < NKT; ++kt) {
            if (kt == 0) {
                // unhidden load of first k-tile of this ct
                #pragma unroll
                for (int t = 0; t < 2; ++t) {
                    int f = tid + t * 256;
                    int v4 = f & 3, g = (f >> 2) & 3, kk = f >> 4;
                    zpf[t] = *(const float4*)(x + (size_t)(bl0 + g) * 4096 + (kt * BK + kk) * 16 + v4 * 4);
                }
                #pragma unroll
                for (int t = 0; t < 8; ++t) {
                    int f = tid + t * 256;
                    int c = f & 255, k4 = f >> 8;
                    epf[t] = *(const float4*)(emb + (size_t)(ct * BN + c) * A_DIM + kt * BK + k4 * 4);
                }
            }
            __syncthreads();           // prior compute done with LDS
            // stage zs[k][row] from regs
            #pragma unroll
            for (int t = 0; t < 2; ++t) {
                int f = tid + t * 256;
                int v4 = f & 3, g = (f >> 2) & 3, kk = f >> 4;
                *(float4*)&sm.zs[kk][g * 16 + v4 * 4] = zpf[t];
            }
            // stage es[k][cand] (transposed) from regs
            #pragma unroll
            for (int t = 0; t < 8; ++t) {
                int f = tid + t * 256;
                int c = f & 255, k4 = f >> 8;
                sm.es[k4 * 4 + 0][c] = epf[t].x;
                sm.es[k4 * 4 + 1][c] = epf[t].y;
                sm.es[k4 * 4 + 2][c] = epf[t].z;
                sm.es[k4 * 4 + 3][c] = epf[t].w;
            }
            __syncthreads();
            // prefetch next k-tile (lands during compute below)
            if (kt + 1 < NKT) {
                #pragma unroll
                for (int t = 0; t < 2; ++t) {
                    int f = tid + t * 256;
                    int v4 = f & 3, g = (f >> 2) & 3, kk = f >> 4;
                    zpf[t] = *(const float4*)(x + (size_t)(bl0 + g) * 4096 + ((kt + 1) * BK + kk) * 16 + v4 * 4);
                }
                #pragma unroll
                for (int t = 0; t < 8; ++t) {
                    int f = tid + t * 256;
                    int c = f & 255, k4 = f >> 8;
                    epf[t] = *(const float4*)(emb + (size_t)(ct * BN + c) * A_DIM + (kt + 1) * BK + k4 * 4);
                }
            }
            // zsq partials (ct==0 covers full K; wave-uniform branch)
            if (ct == 0 && (kt >> 1) == zq4) {
                #pragma unroll
                for (int kk = 0; kk < BK; ++kk) {
                    float zf = sm.zs[kk][zrow_id];
                    float zf2 = zf * zf;           // np squares in f32
                    zsqp += (double)zf2;
                }
            }

            #pragma unroll 2
            for (int kk = 0; kk < BK; ++kk) {
                float4 za = *(float4*)&sm.zs[kk][ty * 4];
                float4 zb = *(float4*)&sm.zs[kk][32 + ty * 4];
                float4 ea = *(float4*)&sm.es[kk][tx * 4];
                float4 eb = *(float4*)&sm.es[kk][128 + tx * 4];
                float zv[8] = {za.x, za.y, za.z, za.w, zb.x, zb.y, zb.z, zb.w};
                float ev[8] = {ea.x, ea.y, ea.z, ea.w, eb.x, eb.y, eb.z, eb.w};
                #pragma unroll
                for (int rr = 0; rr < 8; ++rr)
                    #pragma unroll
                    for (int cc = 0; cc < 8; ++cc)
                        acc[rr][cc] = fmaf(zv[rr], ev[cc], acc[rr][cc]);
            }
        }

        if (ct == 0) {
            // finalize zsq_f32 per row (quarters summed in ascending-k order)
            sm.zsqp_s[zq4][zrow_id] = zsqp;
            __syncthreads();
            if (tid < BM)
                sm.zsq[tid] = (float)(sm.zsqp_s[0][tid] + sm.zsqp_s[1][tid]
                                    + sm.zsqp_s[2][tid] + sm.zsqp_s[3][tid]);
            __syncthreads();
        }

        // emulated-np-f32 scores + top-2 (per-thread cand order ascending in cc)
        float esqv[8];
        #pragma unroll
        for (int cc = 0; cc < 8; ++cc) {
            int c = ct * BN + (cc >> 2) * 128 + tx * 4 + (cc & 3);
            esqv[cc] = e_sq32[c];
        }
        #pragma unroll
        for (int rr = 0; rr < 8; ++rr) {
            int R = (rr >> 2) * 32 + ty * 4 + (rr & 3);
            float zq = sm.zsq[R];
            #pragma unroll
            for (int cc = 0; cc < 8; ++cc) {
                int c = ct * BN + (cc >> 2) * 128 + tx * 4 + (cc & 3);
                float A = zq + esqv[cc];                    // fl32(zsq + esq)
                float s = fmaf(-2.0f, acc[rr][cc], A);      // fl32(A - 2*dot)
                if (s < v1[rr]) { v2[rr] = v1[rr]; i2[rr] = i1[rr]; v1[rr] = s; i1[rr] = c; }
                else if (s < v2[rr]) { v2[rr] = s; i2[rr] = c; }
            }
        }
    }

    // ---- Phase 2: cross-thread merge per row ----
    __syncthreads();
    #pragma unroll
    for (int rr = 0; rr < 8; ++rr) {
        int r = (rr >> 2) * 32 + ty * 4 + (rr & 3);
        float4 m;
        m.x = v1[rr]; m.y = __int_as_float(i1[rr]);
        m.z = v2[rr]; m.w = __int_as_float(i2[rr]);
        sm.mbuf[r][tx] = m;
    }
    __syncthreads();
    if (tid < BM) {
        int r = tid;
        float V1 = 3.0e38f, V2 = 3.0e38f;
        int I1 = 0, I2 = 0;
        for (int t = 0; t < 32; ++t) {
            float4 m = sm.mbuf[r][t];
            float a1 = m.x; int a1i = __float_as_int(m.y);
            float a2 = m.z; int a2i = __float_as_int(m.w);
            if (a1 < V1 || (a1 == V1 && a1i < I1)) { V2 = V1; I2 = I1; V1 = a1; I1 = a1i; }
            else if (a1 < V2 || (a1 == V2 && a1i < I2)) { V2 = a1; I2 = a1i; }
            if (a2 < V1 || (a2 == V1 && a2i < I1)) { V2 = V1; I2 = I1; V1 = a2; I1 = a2i; }
            else if (a2 < V2 || (a2 == V2 && a2i < I2)) { V2 = a2; I2 = a2i; }
        }
        sm.tok[r] = I1;
        if (V2 - V1 <= TAU) {
            int pos = atomicAdd(&sm.nflag, 1);
            sm.flagrows[pos] = r;
        }
    }
    __syncthreads();

    // ---- Phase 3: f64-dot re-emulation of near-tie rows (~1-2 rows/block) ----
    const int nf = sm.nflag;
    for (int i = 0; i < nf; ++i) {
        const int rl = sm.flagrows[i];
        const int bl = bl0 + (rl >> 4);
        const int v  = rl & 15;
        const float zqrow = sm.zsq[rl];
        sm.zrow[tid] = (double)x[(size_t)bl * 4096 + (size_t)tid * 16 + v];
        __syncthreads();
        float bv = 3.0e38f; int bi = 0;
        #pragma unroll
        for (int cc = 0; cc < 4; ++cc) {
            int c = tid * 4 + cc;
            const float4* er = (const float4*)(emb + (size_t)c * A_DIM);
            double dot = 0.0;
            #pragma unroll 8
            for (int k4 = 0; k4 < A_DIM / 4; ++k4) {
                float4 f = er[k4];
                dot = fma((double)f.x, sm.zrow[k4 * 4 + 0], dot);
                dot = fma((double)f.y, sm.zrow[k4 * 4 + 1], dot);
                dot = fma((double)f.z, sm.zrow[k4 * 4 + 2], dot);
                dot = fma((double)f.w, sm.zrow[k4 * 4 + 3], dot);
            }
            float A = zqrow + e_sq32[c];        // fl32(zsq + esq)
            float D = (float)(2.0 * dot);       // fl32(2*dot), correctly rounded
            float s = A - D;                    // fl32(A - D)
            if (s < bv) { bv = s; bi = c; }     // ascending c: strict < keeps first
        }
        sm.rbest[tid] = bv; sm.ridx[tid] = bi;
        __syncthreads();
        if (tid == 0) {
            float BV = sm.rbest[0]; int BI = sm.ridx[0];
            for (int t = 1; t < 256; ++t) {
                float vv = sm.rbest[t];
                if (vv < BV) { BV = vv; BI = sm.ridx[t]; }
            }
            sm.tok[rl] = BI;
        }
        __syncthreads();
    }

    // ---- Phase 4: tokens as float32 ----
    if (tid < BM) {
        out[2 * ZQ_ELEMS + (size_t)(row0 + tid)] = (float)sm.tok[tid];
    }
    __syncthreads();

    // ---- Phase 5: z_q and decoder_input (float32) ----
    const int a = tid;  // 0..255
    for (int g = 0; g < 4; ++g) {
        __align__(16) float h[16];
        #pragma unroll
        for (int v = 0; v < 16; ++v) {
            h[v] = emb[(size_t)sm.tok[g * 16 + v] * A_DIM + a];
        }
        size_t base = ((size_t)(bl0 + g) * A_DIM + a) * 16;
        float4* p0 = (float4*)(out + base);
        float4* p1 = (float4*)(out + ZQ_ELEMS + base);
        #pragma unroll
        for (int q = 0; q < 4; ++q) {
            float4 val = *(float4*)&h[q * 4];
            p0[q] = val;
            p1[q] = val;
        }
    }
}

extern "C" void kernel_launch(void* const* d_in, const int* in_sizes, int n_in,
                              void* d_out, int out_size, void* d_ws, size_t ws_size,
                              hipStream_t stream) {
    (void)in_sizes; (void)n_in; (void)out_size; (void)ws_size;
    const float* x   = (const float*)d_in[0];
    const float* emb = (const float*)d_in[1];
    float* out = (float*)d_out;
    float* e_sq32 = (float*)d_ws;

    prep_kernel<<<4, 256, 0, stream>>>(emb, e_sq32);
    main_kernel<<<512, 256, 0, stream>>>(x, emb, e_sq32, out);
}

// Round 7
// 374.053 us; speedup vs baseline: 2.3773x; 1.8318x over previous
//
#include <hip/hip_runtime.h>

// x (64,32,4096) fp32; emb (1024,256) fp32.
// Row n = bl*16 + v (bl = b*32+l); z_flat[n][a] = x[bl*4096 + a*16 + v].
// Outputs FLOAT32, concat: z_q [8388608] (b,l,a,v), decoder_input [8388608]
// (== z_q forward), tokens [32768] (b,l,v).
//
// np reference computes dist = z_sq + e_sq - 2*(z@e.T) in float32 (score ulp
// ~3.05e-5 at zsq~256). Strategy: fp16 MFMA coarse scoring (esq - 2*dot, zsq
// dropped: per-row constant), flag rows with top-2 margin <= TAU_C = 3e-4
// (covers fp16 quantization + f32 outer-rounding deterministically-ish at
// >20 sigma), exact f64-dot + f32-outer-emulated rescan for flagged rows
// (identical numerics to the round-4/5 PASSING kernel's phase 3).

#define A_DIM 256
#define VOCAB 1024
#define NROWS 32768
#define ZQ_ELEMS ((size_t)8388608)
#define TAU_C 3.0e-4f
#define TAU_F 2.0e-4f

typedef _Float16 f16x8 __attribute__((ext_vector_type(8)));
typedef float f32x4 __attribute__((ext_vector_type(4)));

// ---- ws layout (bytes) ----
#define WS_EHT   ((size_t)0)         // _Float16 [32][1024][8]  = 524288
#define WS_ZH    ((size_t)524288)    // _Float16 [32768][256]   = 16777216
#define WS_ESQ   ((size_t)17301504)  // float [1024]            = 4096
#define WS_ZSQ   ((size_t)17305600)  // float [32768]           = 131072
#define WS_HALF  ((size_t)17436672)  // float4 [32768][2]       = 1048576
#define WS_TOK   ((size_t)18485248)  // int [32768]             = 131072
#define WS_LIST  ((size_t)18616320)  // int [32768]             = 131072
#define WS_CNT   ((size_t)18747392)  // int
#define WS_NEED  ((size_t)18747520)

// ================= fast path =================

// esq (np-f32-emulated) + eh_t fp16 in [k/8][cand][8] layout
__global__ __launch_bounds__(256) void prep_e_kernel(const float* __restrict__ emb,
                                                     float* __restrict__ esq,
                                                     _Float16* __restrict__ eht) {
    int j = blockIdx.x * 256 + threadIdx.x;
    if (j >= VOCAB) return;
    const float4* row = (const float4*)(emb + (size_t)j * A_DIM);
    double s = 0.0;
    #pragma unroll 4
    for (int t = 0; t < A_DIM / 4; ++t) {
        float4 f = row[t];
        float sx = f.x * f.x, sy = f.y * f.y, sz = f.z * f.z, sw = f.w * f.w;
        s += (double)sx + (double)sy + (double)sz + (double)sw;
    }
    esq[j] = (float)s;
    #pragma unroll 4
    for (int kb = 0; kb < 32; ++kb) {
        float4 e0 = row[kb * 2], e1 = row[kb * 2 + 1];
        f16x8 h;
        h[0] = (_Float16)e0.x; h[1] = (_Float16)e0.y; h[2] = (_Float16)e0.z; h[3] = (_Float16)e0.w;
        h[4] = (_Float16)e1.x; h[5] = (_Float16)e1.y; h[6] = (_Float16)e1.z; h[7] = (_Float16)e1.w;
        *(f16x8*)(eht + ((size_t)kb * 1024 + j) * 8) = h;
    }
}

// zh fp16 [row][k] (transposed from x) + zsq (f64 sum of f32 squares -> f32)
__global__ __launch_bounds__(256) void prep_z_kernel(const float* __restrict__ x,
                                                     _Float16* __restrict__ zh,
                                                     float* __restrict__ zsq,
                                                     int* __restrict__ count) {
    __shared__ float raw[A_DIM * 17];  // [a*17 + v], padded to kill conflicts
    const int tid = threadIdx.x;
    const int bl = blockIdx.x;         // 0..2047
    if (bl == 0 && tid == 0) *count = 0;
    #pragma unroll
    for (int t = 0; t < 16; ++t) {
        int f = tid + t * 256;         // = a*16 + v
        raw[(f >> 4) * 17 + (f & 15)] = x[(size_t)bl * 4096 + f];
    }
    __syncthreads();
    #pragma unroll
    for (int t = 0; t < 16; ++t) {
        int f = tid + t * 256;
        int v = f >> 8, a = f & 255;
        zh[((size_t)bl * 16 + v) * 256 + a] = (_Float16)raw[a * 17 + v];
    }
    if (tid < 16) {
        double s = 0.0;
        for (int a = 0; a < A_DIM; ++a) {
            float zf = raw[a * 17 + tid];
            float z2 = zf * zf;            // np squares in f32
            s += (double)z2;
        }
        zsq[bl * 16 + tid] = (float)s;
    }
}

// MFMA coarse scorer: block = 128 rows x 512 cands (half), 4 waves x 32 rows
__global__ __launch_bounds__(256, 2) void mfma_kernel(const _Float16* __restrict__ zh,
                                                      const _Float16* __restrict__ eht,
                                                      const float* __restrict__ esq_g,
                                                      float4* __restrict__ halfres) {
    __shared__ __align__(16) _Float16 lb[32 * 64 * 8];  // 32 KB: [kb 0..31][c 0..63][8]
    const int tid = threadIdx.x;
    const int w = tid >> 6;            // wave 0..3
    const int lane = tid & 63;
    const int q = lane >> 4;           // quad
    const int ln = lane & 15;
    const int blk = blockIdx.x;        // 0..511
    const int rowblk = blk >> 1;
    const int half = blk & 1;
    const int row0 = rowblk * 128 + w * 32;

    // A-fragment register cache: 2 M-tiles x 8 k-steps
    f16x8 afr[2][8];
    #pragma unroll
    for (int mt = 0; mt < 2; ++mt)
        #pragma unroll
        for (int kt = 0; kt < 8; ++kt)
            afr[mt][kt] = *(const f16x8*)(zh + (size_t)(row0 + mt * 16 + ln) * 256 + kt * 32 + q * 8);

    float tv1[8], tv2[8];
    int   ti1[8], ti2[8];
    #pragma unroll
    for (int s = 0; s < 8; ++s) { tv1[s] = 3.0e38f; tv2[s] = 3.0e38f; ti1[s] = 0; ti2[s] = 0; }

    for (int chunk = 0; chunk < 8; ++chunk) {
        const int c0 = half * 512 + chunk * 64;
        __syncthreads();
        // stage eh_t chunk: 64 cands x 256 k = 32 KB, coalesced + conflict-free
        #pragma unroll
        for (int t = 0; t < 8; ++t) {
            int f = tid + t * 256;
            int kb = f >> 6, c = f & 63;
            *(f16x8*)&lb[((size_t)kb * 64 + c) * 8] =
                *(const f16x8*)(eht + ((size_t)kb * 1024 + c0 + c) * 8);
        }
        __syncthreads();

        f32x4 acc[2][4];
        #pragma unroll
        for (int mt = 0; mt < 2; ++mt)
            #pragma unroll
            for (int nt = 0; nt < 4; ++nt)
                acc[mt][nt] = (f32x4){0.f, 0.f, 0.f, 0.f};

        #pragma unroll
        for (int kt = 0; kt < 8; ++kt) {
            #pragma unroll
            for (int nt = 0; nt < 4; ++nt) {
                f16x8 bfr = *(const f16x8*)&lb[(((size_t)kt * 4 + q) * 64 + nt * 16 + ln) * 8];
                acc[0][nt] = __builtin_amdgcn_mfma_f32_16x16x32_f16(afr[0][kt], bfr, acc[0][nt], 0, 0, 0);
                acc[1][nt] = __builtin_amdgcn_mfma_f32_16x16x32_f16(afr[1][kt], bfr, acc[1][nt], 0, 0, 0);
            }
        }

        // coarse scores (zsq omitted: per-row constant) + top-2
        #pragma unroll
        for (int nt = 0; nt < 4; ++nt) {
            int c = c0 + nt * 16 + ln;
            float es = esq_g[c];
            #pragma unroll
            for (int mt = 0; mt < 2; ++mt) {
                #pragma unroll
                for (int reg = 0; reg < 4; ++reg) {
                    float s = fmaf(-2.0f, acc[mt][nt][reg], es);
                    int slot = mt * 4 + reg;
                    if (s < tv1[slot]) { tv2[slot] = tv1[slot]; ti2[slot] = ti1[slot];
                                         tv1[slot] = s; ti1[slot] = c; }
                    else if (s < tv2[slot]) { tv2[slot] = s; ti2[slot] = c; }
                }
            }
        }
    }

    // butterfly top-2 merge across the 16 lanes of each quad
    #pragma unroll
    for (int slot = 0; slot < 8; ++slot) {
        float v1 = tv1[slot], v2 = tv2[slot];
        int i1 = ti1[slot], i2 = ti2[slot];
        #pragma unroll
        for (int m = 1; m <= 8; m <<= 1) {
            float ov1 = __shfl_xor(v1, m); int oi1 = __shfl_xor(i1, m);
            float ov2 = __shfl_xor(v2, m); int oi2 = __shfl_xor(i2, m);
            if (ov1 < v1 || (ov1 == v1 && oi1 < i1)) { v2 = v1; i2 = i1; v1 = ov1; i1 = oi1; }
            else if (ov1 < v2 || (ov1 == v2 && oi1 < i2)) { v2 = ov1; i2 = oi1; }
            if (ov2 < v2 || (ov2 == v2 && oi2 < i2)) {
                if (ov2 < v1 || (ov2 == v1 && oi2 < i1)) { v2 = v1; i2 = i1; v1 = ov2; i1 = oi2; }
                else { v2 = ov2; i2 = oi2; }
            }
        }
        if (ln == 0) {
            int row = row0 + (slot >> 2) * 16 + q * 4 + (slot & 3);
            halfres[(size_t)row * 2 + half] =
                make_float4(v1, __int_as_float(i1), v2, __int_as_float(i2));
        }
    }
}

// merge halves, write tokens, flag near-ties
__global__ __launch_bounds__(256) void finalize_kernel(const float4* __restrict__ halfres,
                                                       int* __restrict__ tok,
                                                       int* __restrict__ list,
                                                       int* __restrict__ count,
                                                       float* __restrict__ out) {
    int row = blockIdx.x * 256 + threadIdx.x;
    float4 h0 = halfres[(size_t)row * 2];
    float4 h1 = halfres[(size_t)row * 2 + 1];
    float V1 = h0.x; int I1 = __float_as_int(h0.y);
    float V2 = h0.z; int I2 = __float_as_int(h0.w);
    float a1 = h1.x; int b1 = __float_as_int(h1.y);
    if (a1 < V1) { V2 = V1; I2 = I1; V1 = a1; I1 = b1; }
    else if (a1 < V2) { V2 = a1; I2 = b1; }
    float a2 = h1.z; int b2 = __float_as_int(h1.w);
    if (a2 < V2) {
        if (a2 < V1) { V2 = V1; I2 = I1; V1 = a2; I1 = b2; }
        else { V2 = a2; I2 = b2; }
    }
    tok[row] = I1;
    out[2 * ZQ_ELEMS + (size_t)row] = (float)I1;
    if (V2 - V1 <= TAU_C) {
        int p = atomicAdd(count, 1);
        list[p] = row;
    }
}

// exact rescan of flagged rows: f64 dots, f32 outer ops (np-emulated),
// first-index tie-break. Batches 8 rows/block to amortize emb traffic.
__global__ __launch_bounds__(256) void rescan_kernel(const float* __restrict__ x,
                                                     const float* __restrict__ emb,
                                                     const float* __restrict__ esq,
                                                     const float* __restrict__ zsq,
                                                     int* __restrict__ tok,
                                                     const int* __restrict__ list,
                                                     const int* __restrict__ count,
                                                     float* __restrict__ out) {
    __shared__ double zr[8][A_DIM];
    __shared__ float zsqs[8];
    __shared__ int rowss[8];
    __shared__ float redv[8][256];
    __shared__ int redi[8][256];
    const int tid = threadIdx.x;
    const int n = *count;
    for (int base = blockIdx.x * 8; base < n; base += gridDim.x * 8) {
        const int m = min(8, n - base);
        if (tid < m) { int r = list[base + tid]; rowss[tid] = r; zsqs[tid] = zsq[r]; }
        __syncthreads();
        for (int j = 0; j < m; ++j) {
            int r = rowss[j];
            zr[j][tid] = (double)x[(size_t)(r >> 4) * 4096 + (size_t)tid * 16 + (r & 15)];
        }
        __syncthreads();
        float bv[8]; int bi[8];
        #pragma unroll
        for (int j = 0; j < 8; ++j) { bv[j] = 3.0e38f; bi[j] = 0; }
        for (int cc = 0; cc < 4; ++cc) {
            int c = tid * 4 + cc;
            const float4* er = (const float4*)(emb + (size_t)c * A_DIM);
            double d[8];
            #pragma unroll
            for (int j = 0; j < 8; ++j) d[j] = 0.0;
            for (int k4 = 0; k4 < A_DIM / 4; ++k4) {
                float4 f = er[k4];
                double e0 = (double)f.x, e1 = (double)f.y, e2 = (double)f.z, e3 = (double)f.w;
                for (int j = 0; j < m; ++j) {
                    double s = fma(e0, zr[j][k4 * 4 + 0], d[j]);
                    s = fma(e1, zr[j][k4 * 4 + 1], s);
                    s = fma(e2, zr[j][k4 * 4 + 2], s);
                    s = fma(e3, zr[j][k4 * 4 + 3], s);
                    d[j] = s;
                }
            }
            float es = esq[c];
            for (int j = 0; j < m; ++j) {
                float A = zsqs[j] + es;            // fl32(zsq + esq)
                float D = (float)(2.0 * d[j]);     // fl32(2*dot)
                float s = A - D;                   // fl32(A - D)
                if (s < bv[j]) { bv[j] = s; bi[j] = c; }  // ascending cc
            }
        }
        for (int j = 0; j < m; ++j) { redv[j][tid] = bv[j]; redi[j][tid] = bi[j]; }
        __syncthreads();
        if (tid < m) {
            float BV = redv[tid][0]; int BI = redi[tid][0];
            for (int t = 1; t < 256; ++t) {
                float vv = redv[tid][t];
                if (vv < BV) { BV = vv; BI = redi[tid][t]; }   // ascending c
            }
            int r = rowss[tid];
            tok[r] = BI;
            out[2 * ZQ_ELEMS + (size_t)r] = (float)BI;
        }
        __syncthreads();
    }
}

// gather epilogue: z_q + decoder_input
__global__ __launch_bounds__(256) void gather_kernel(const float* __restrict__ emb,
                                                     const int* __restrict__ tok,
                                                     float* __restrict__ out) {
    __shared__ int t16[16];
    const int tid = threadIdx.x;
    const int bl = blockIdx.x;
    if (tid < 16) t16[tid] = tok[bl * 16 + tid];
    __syncthreads();
    const int a = tid;
    __align__(16) float h[16];
    #pragma unroll
    for (int v = 0; v < 16; ++v) h[v] = emb[(size_t)t16[v] * A_DIM + a];
    size_t base = ((size_t)bl * A_DIM + a) * 16;
    float4* p0 = (float4*)(out + base);
    float4* p1 = (float4*)(out + ZQ_ELEMS + base);
    #pragma unroll
    for (int qq = 0; qq < 4; ++qq) {
        float4 val = *(float4*)&h[qq * 4];
        p0[qq] = val;
        p1[qq] = val;
    }
}

// ================= fallback path (round-5 PASSING kernel, verbatim) =================

__global__ __launch_bounds__(256) void prep_f(const float* __restrict__ emb,
                                              float* __restrict__ e_sq32) {
    int j = blockIdx.x * 256 + threadIdx.x;
    if (j < VOCAB) {
        const float4* row = (const float4*)(emb + (size_t)j * A_DIM);
        double s = 0.0;
        #pragma unroll 4
        for (int t = 0; t < A_DIM / 4; ++t) {
            float4 f = row[t];
            float sx = f.x * f.x, sy = f.y * f.y, sz = f.z * f.z, sw = f.w * f.w;
            s += (double)sx + (double)sy + (double)sz + (double)sw;
        }
        e_sq32[j] = (float)s;
    }
}

#define FBM 64
#define FBN 256
#define FBK 32
struct SmemF {
    union {
        struct { float zs[FBK][FBM]; float es[FBK][FBN]; };
        float4 mbuf[FBM][32];
        struct { double zrow[A_DIM]; float rbest[256]; int ridx[256]; };
    };
    double zsqp_s[4][FBM];
    float  zsq[FBM];
    int    tok[FBM];
    int    flagrows[FBM];
    int    nflag;
};

__global__ __launch_bounds__(256, 2) void main_f(const float* __restrict__ x,
                                                 const float* __restrict__ emb,
                                                 const float* __restrict__ e_sq32,
                                                 float* __restrict__ out) {
    __shared__ SmemF sm;
    const int tid = threadIdx.x;
    const int tx = tid & 31;
    const int ty = tid >> 5;
    const int blk = blockIdx.x;
    const int row0 = blk * FBM;
    const int bl0 = row0 >> 4;
    const int zrow_id = tid & 63;
    const int zq4     = tid >> 6;

    if (tid == 0) sm.nflag = 0;
    float v1[8], v2[8];
    int   i1[8], i2[8];
    #pragma unroll
    for (int r = 0; r < 8; ++r) { v1[r] = 3.0e38f; v2[r] = 3.0e38f; i1[r] = 0; i2[r] = 0; }
    double zsqp = 0.0;
    float4 zpf[2];
    float4 epf[8];
    for (int ct = 0; ct < VOCAB / FBN; ++ct) {
        float acc[8][8];
        #pragma unroll
        for (int rr = 0; rr < 8; ++rr)
            #pragma unroll
            for (int cc = 0; cc < 8; ++cc) acc[rr][cc] = 0.0f;
        for (int kt = 0; kt < A_DIM / FBK; ++kt) {
            if (kt == 0) {
                #pragma unroll
                for (int t = 0; t < 2; ++t) {
                    int f = tid + t * 256;
                    int v4 = f & 3, g = (f >> 2) & 3, kk = f >> 4;
                    zpf[t] = *(const float4*)(x + (size_t)(bl0 + g) * 4096 + (kt * FBK + kk) * 16 + v4 * 4);
                }
                #pragma unroll
                for (int t = 0; t < 8; ++t) {
                    int f = tid + t * 256;
                    int c = f & 255, k4 = f >> 8;
                    epf[t] = *(const float4*)(emb + (size_t)(ct * FBN + c) * A_DIM + kt * FBK + k4 * 4);
                }
            }
            __syncthreads();
            #pragma unroll
            for (int t = 0; t < 2; ++t) {
                int f = tid + t * 256;
                int v4 = f & 3, g = (f >> 2) & 3, kk = f >> 4;
                *(float4*)&sm.zs[kk][g * 16 + v4 * 4] = zpf[t];
            }
            #pragma unroll
            for (int t = 0; t < 8; ++t) {
                int f = tid + t * 256;
                int c = f & 255, k4 = f >> 8;
                sm.es[k4 * 4 + 0][c] = epf[t].x;
                sm.es[k4 * 4 + 1][c] = epf[t].y;
                sm.es[k4 * 4 + 2][c] = epf[t].z;
                sm.es[k4 * 4 + 3][c] = epf[t].w;
            }
            __syncthreads();
            if (kt + 1 < A_DIM / FBK) {
                #pragma unroll
                for (int t = 0; t < 2; ++t) {
                    int f = tid + t * 256;
                    int v4 = f & 3, g = (f >> 2) & 3, kk = f >> 4;
                    zpf[t] = *(const float4*)(x + (size_t)(bl0 + g) * 4096 + ((kt + 1) * FBK + kk) * 16 + v4 * 4);
                }
                #pragma unroll
                for (int t = 0; t < 8; ++t) {
                    int f = tid + t * 256;
                    int c = f & 255, k4 = f >> 8;
                    epf[t] = *(const float4*)(emb + (size_t)(ct * FBN + c) * A_DIM + (kt + 1) * FBK + k4 * 4);
                }
            }
            if (ct == 0 && (kt >> 1) == zq4) {
                #pragma unroll
                for (int kk = 0; kk < FBK; ++kk) {
                    float zf = sm.zs[kk][zrow_id];
                    float zf2 = zf * zf;
                    zsqp += (double)zf2;
                }
            }
            #pragma unroll 2
            for (int kk = 0; kk < FBK; ++kk) {
                float4 za = *(float4*)&sm.zs[kk][ty * 4];
                float4 zb = *(float4*)&sm.zs[kk][32 + ty * 4];
                float4 ea = *(float4*)&sm.es[kk][tx * 4];
                float4 eb = *(float4*)&sm.es[kk][128 + tx * 4];
                float zv[8] = {za.x, za.y, za.z, za.w, zb.x, zb.y, zb.z, zb.w};
                float ev[8] = {ea.x, ea.y, ea.z, ea.w, eb.x, eb.y, eb.z, eb.w};
                #pragma unroll
                for (int rr = 0; rr < 8; ++rr)
                    #pragma unroll
                    for (int cc = 0; cc < 8; ++cc)
                        acc[rr][cc] = fmaf(zv[rr], ev[cc], acc[rr][cc]);
            }
        }
        if (ct == 0) {
            sm.zsqp_s[zq4][zrow_id] = zsqp;
            __syncthreads();
            if (tid < FBM)
                sm.zsq[tid] = (float)(sm.zsqp_s[0][tid] + sm.zsqp_s[1][tid]
                                    + sm.zsqp_s[2][tid] + sm.zsqp_s[3][tid]);
            __syncthreads();
        }
        float esqv[8];
        #pragma unroll
        for (int cc = 0; cc < 8; ++cc) {
            int c = ct * FBN + (cc >> 2) * 128 + tx * 4 + (cc & 3);
            esqv[cc] = e_sq32[c];
        }
        #pragma unroll
        for (int rr = 0; rr < 8; ++rr) {
            int R = (rr >> 2) * 32 + ty * 4 + (rr & 3);
            float zq = sm.zsq[R];
            #pragma unroll
            for (int cc = 0; cc < 8; ++cc) {
                int c = ct * FBN + (cc >> 2) * 128 + tx * 4 + (cc & 3);
                float A = zq + esqv[cc];
                float s = fmaf(-2.0f, acc[rr][cc], A);
                if (s < v1[rr]) { v2[rr] = v1[rr]; i2[rr] = i1[rr]; v1[rr] = s; i1[rr] = c; }
                else if (s < v2[rr]) { v2[rr] = s; i2[rr] = c; }
            }
        }
    }
    __syncthreads();
    #pragma unroll
    for (int rr = 0; rr < 8; ++rr) {
        int r = (rr >> 2) * 32 + ty * 4 + (rr & 3);
        float4 m;
        m.x = v1[rr]; m.y = __int_as_float(i1[rr]);
        m.z = v2[rr]; m.w = __int_as_float(i2[rr]);
        sm.mbuf[r][tx] = m;
    }
    __syncthreads();
    if (tid < FBM) {
        int r = tid;
        float V1 = 3.0e38f, V2 = 3.0e38f;
        int I1 = 0, I2 = 0;
        for (int t = 0; t < 32; ++t) {
            float4 m = sm.mbuf[r][t];
            float a1 = m.x; int a1i = __float_as_int(m.y);
            float a2 = m.z; int a2i = __float_as_int(m.w);
            if (a1 < V1 || (a1 == V1 && a1i < I1)) { V2 = V1; I2 = I1; V1 = a1; I1 = a1i; }
            else if (a1 < V2 || (a1 == V2 && a1i < I2)) { V2 = a1; I2 = a1i; }
            if (a2 < V1 || (a2 == V1 && a2i < I1)) { V2 = V1; I2 = I1; V1 = a2; I1 = a2i; }
            else if (a2 < V2 || (a2 == V2 && a2i < I2)) { V2 = a2; I2 = a2i; }
        }
        sm.tok[r] = I1;
        if (V2 - V1 <= TAU_F) {
            int pos = atomicAdd(&sm.nflag, 1);
            sm.flagrows[pos] = r;
        }
    }
    __syncthreads();
    const int nf = sm.nflag;
    for (int i = 0; i < nf; ++i) {
        const int rl = sm.flagrows[i];
        const int bl = bl0 + (rl >> 4);
        const int v  = rl & 15;
        const float zqrow = sm.zsq[rl];
        sm.zrow[tid] = (double)x[(size_t)bl * 4096 + (size_t)tid * 16 + v];
        __syncthreads();
        float bv = 3.0e38f; int bi = 0;
        #pragma unroll
        for (int cc = 0; cc < 4; ++cc) {
            int c = tid * 4 + cc;
            const float4* er = (const float4*)(emb + (size_t)c * A_DIM);
            double dot = 0.0;
            #pragma unroll 8
            for (int k4 = 0; k4 < A_DIM / 4; ++k4) {
                float4 f = er[k4];
                dot = fma((double)f.x, sm.zrow[k4 * 4 + 0], dot);
                dot = fma((double)f.y, sm.zrow[k4 * 4 + 1], dot);
                dot = fma((double)f.z, sm.zrow[k4 * 4 + 2], dot);
                dot = fma((double)f.w, sm.zrow[k4 * 4 + 3], dot);
            }
            float A = zqrow + e_sq32[c];
            float D = (float)(2.0 * dot);
            float s = A - D;
            if (s < bv) { bv = s; bi = c; }
        }
        sm.rbest[tid] = bv; sm.ridx[tid] = bi;
        __syncthreads();
        if (tid == 0) {
            float BV = sm.rbest[0]; int BI = sm.ridx[0];
            for (int t = 1; t < 256; ++t) {
                float vv = sm.rbest[t];
                if (vv < BV) { BV = vv; BI = sm.ridx[t]; }
            }
            sm.tok[rl] = BI;
        }
        __syncthreads();
    }
    if (tid < FBM) {
        out[2 * ZQ_ELEMS + (size_t)(row0 + tid)] = (float)sm.tok[tid];
    }
    __syncthreads();
    const int a = tid;
    for (int g = 0; g < 4; ++g) {
        __align__(16) float h[16];
        #pragma unroll
        for (int v = 0; v < 16; ++v) {
            h[v] = emb[(size_t)sm.tok[g * 16 + v] * A_DIM + a];
        }
        size_t base = ((size_t)(bl0 + g) * A_DIM + a) * 16;
        float4* p0 = (float4*)(out + base);
        float4* p1 = (float4*)(out + ZQ_ELEMS + base);
        #pragma unroll
        for (int qq = 0; qq < 4; ++qq) {
            float4 val = *(float4*)&h[qq * 4];
            p0[qq] = val;
            p1[qq] = val;
        }
    }
}

extern "C" void kernel_launch(void* const* d_in, const int* in_sizes, int n_in,
                              void* d_out, int out_size, void* d_ws, size_t ws_size,
                              hipStream_t stream) {
    (void)in_sizes; (void)n_in; (void)out_size;
    const float* x   = (const float*)d_in[0];
    const float* emb = (const float*)d_in[1];
    float* out = (float*)d_out;
    char* ws = (char*)d_ws;

    if (ws_size >= WS_NEED) {
        _Float16* eht = (_Float16*)(ws + WS_EHT);
        _Float16* zh  = (_Float16*)(ws + WS_ZH);
        float* esq    = (float*)(ws + WS_ESQ);
        float* zsq    = (float*)(ws + WS_ZSQ);
        float4* half_ = (float4*)(ws + WS_HALF);
        int* tok      = (int*)(ws + WS_TOK);
        int* list     = (int*)(ws + WS_LIST);
        int* count    = (int*)(ws + WS_CNT);

        prep_e_kernel<<<4, 256, 0, stream>>>(emb, esq, eht);
        prep_z_kernel<<<2048, 256, 0, stream>>>(x, zh, zsq, count);
        mfma_kernel<<<512, 256, 0, stream>>>(zh, eht, esq, half_);
        finalize_kernel<<<128, 256, 0, stream>>>(half_, tok, list, count, out);
        rescan_kernel<<<512, 256, 0, stream>>>(x, emb, esq, zsq, tok, list, count, out);
        gather_kernel<<<2048, 256, 0, stream>>>(emb, tok, out);
    } else {
        float* e_sq32 = (float*)ws;
        prep_f<<<4, 256, 0, stream>>>(emb, e_sq32);
        main_f<<<512, 256, 0, stream>>>(x, emb, e_sq32, out);
    }
}